// Round 9
// baseline (891.055 us; speedup 1.0000x reference)
//
#include <hip/hip_runtime.h>
#include <cstdint>
#include <cstddef>

#define HD 128
#define EDGED 16
#define NODED 64
#define LN_EPS 1e-5f

typedef __bf16 bf16x8 __attribute__((ext_vector_type(8)));
typedef float  f32x4  __attribute__((ext_vector_type(4)));
typedef _Float16 half2v __attribute__((ext_vector_type(2)));
typedef _Float16 half4v __attribute__((ext_vector_type(4)));
typedef _Float16 half8v __attribute__((ext_vector_type(8)));

union HU { half8v v; half2v p[4]; };

__device__ __forceinline__ float gelu_exact(float x) {
    return 0.5f * x * (1.0f + erff(x * 0.7071067811865475f));
}

__device__ __forceinline__ float hi16_to_f(int bits) {
    union { unsigned short u; _Float16 h; } c;
    c.u = (unsigned short)((unsigned)bits >> 16);
    return (float)c.h;
}

// fp32 -> bf16 hi/lo split (a ~= hi + lo, lo captures the rounding residual)
__global__ void wconv_k(const float* __restrict__ in, __bf16* __restrict__ hi,
                        __bf16* __restrict__ lo, int n) {
    int i = blockIdx.x * blockDim.x + threadIdx.x;
    if (i < n) {
        float v = in[i];
        __bf16 h = (__bf16)v;
        hi[i] = h;
        lo[i] = (__bf16)(v - (float)h);
    }
}

// fp32 -> fp16 hi/lo split
__global__ void wconv16_k(const float* __restrict__ in, _Float16* __restrict__ hi,
                          _Float16* __restrict__ lo, int n) {
    int i = blockIdx.x * blockDim.x + threadIdx.x;
    if (i < n) {
        float v = in[i];
        _Float16 h = (_Float16)v;
        hi[i] = h;
        lo[i] = (_Float16)(v - (float)h);
    }
}

// ---------------- CSR build ----------------

__global__ void hist_k(const int* __restrict__ ei, int* __restrict__ cnt, int E) {
    int e = blockIdx.x * blockDim.x + threadIdx.x;
    if (e < E) atomicAdd(&cnt[ei[E + e]], 1);
}

__global__ void scan1_k(const int* __restrict__ in, int* __restrict__ out,
                        int* __restrict__ bsum, int n) {
    __shared__ int lds[256];
    int t = threadIdx.x;
    int i = blockIdx.x * 256 + t;
    int v = (i < n) ? in[i] : 0;
    lds[t] = v;
    __syncthreads();
#pragma unroll
    for (int o = 1; o < 256; o <<= 1) {
        int u = (t >= o) ? lds[t - o] : 0;
        __syncthreads();
        lds[t] += u;
        __syncthreads();
    }
    if (i < n) out[i] = lds[t] - v;
    if (t == 255) bsum[blockIdx.x] = lds[255];
}

__global__ void scan2_k(const int* __restrict__ bsum, int* __restrict__ boff, int nb) {
    __shared__ int lds[256];
    int t = threadIdx.x;
    int v = (t < nb) ? bsum[t] : 0;
    lds[t] = v;
    __syncthreads();
#pragma unroll
    for (int o = 1; o < 256; o <<= 1) {
        int u = (t >= o) ? lds[t - o] : 0;
        __syncthreads();
        lds[t] += u;
        __syncthreads();
    }
    if (t < nb) boff[t] = lds[t] - v;
}

// adds block offsets; also emits the scatter cursor copy (saves a d2d memcpy)
__global__ void scan3_k(int* __restrict__ rs, int* __restrict__ cursor,
                        const int* __restrict__ boff, int n, int E) {
    int i = blockIdx.x * 256 + threadIdx.x;
    if (i < n) {
        int v = rs[i] + boff[blockIdx.x];
        rs[i] = v;
        cursor[i] = v;
    }
    if (i == 0) rs[n] = E;
}

__global__ void scatter_k(const int* __restrict__ ei, int* __restrict__ cursor,
                          int2* __restrict__ es, int E) {
    int e = blockIdx.x * blockDim.x + threadIdx.x;
    if (e < E) {
        int dst = ei[E + e];
        int slot = atomicAdd(&cursor[dst], 1);
        es[slot] = make_int2(ei[e], e);
    }
}

// ---------------- edge-LN precompute (+ fused self-loop embed) ----------------
__global__ void prep_k(const float* __restrict__ edge_W, const float* __restrict__ edge_b,
                       const float* __restrict__ edge_g, const float* __restrict__ edge_be,
                       const float* __restrict__ sl_attr, _Float16* __restrict__ Wg16_3,
                       float* __restrict__ bg3, float* __restrict__ M3,
                       float* __restrict__ v3, float* __restrict__ s03,
                       float* __restrict__ slv3)
{
    const int l = blockIdx.x;
    const float* W = edge_W + (size_t)l * HD * EDGED;
    const float* b = edge_b + l * HD;
    const float* g = edge_g + l * HD;
    __shared__ float Wp[HD * EDGED];
    __shared__ float bp[HD];
    __shared__ float wm[EDGED];
    __shared__ float Msh[256];
    __shared__ float vsh[EDGED];
    __shared__ float ash[EDGED];
    __shared__ float bmS, s0sh;
    const int t = threadIdx.x;
#pragma unroll
    for (int m = 0; m < 8; ++m) Wp[m * 256 + t] = W[m * 256 + t];
    __syncthreads();
    if (t < EDGED) {
        float s = 0.f;
        for (int c = 0; c < HD; ++c) s += Wp[c * EDGED + t];
        wm[t] = s * (1.f / HD);
    } else if (t == EDGED) {
        float s = 0.f;
        for (int c = 0; c < HD; ++c) s += b[c];
        bmS = s * (1.f / HD);
    }
    __syncthreads();
    if (t < HD) bp[t] = b[t] - bmS;
    __syncthreads();
#pragma unroll
    for (int m = 0; m < 8; ++m) {
        int idx = m * 256 + t;
        int c = idx >> 4, k = idx & 15;
        float val = Wp[idx] - wm[k];
        Wp[idx] = val;
        Wg16_3[(size_t)l * 2048 + idx] = (_Float16)(val * g[c]);   // [c][k] layout
    }
    if (t < HD) bg3[l * HD + t] = bp[t] * g[t];
    __syncthreads();
    {
        int k = t >> 4, j = t & 15;
        float s = 0.f;
        for (int c = 0; c < HD; ++c) s += Wp[c * EDGED + k] * Wp[c * EDGED + j];
        Msh[t] = s;
        M3[l * 256 + t] = s;
    }
    if (t < EDGED) {
        float s = 0.f;
        for (int c = 0; c < HD; ++c) s += Wp[c * EDGED + t] * bp[c];
        vsh[t] = 2.f * s;
        v3[l * EDGED + t] = 2.f * s;
        ash[t] = sl_attr[l * EDGED + t];
    } else if (t == EDGED) {
        float s = 0.f;
        for (int c = 0; c < HD; ++c) s += bp[c] * bp[c];
        s0sh = s;
        s03[l] = s;
    }
    __syncthreads();
    // self-loop embed: out_c = ((Wp.a)*g + bg)*inv + bet, relu
    if (t < HD) {
        float q = s0sh;
#pragma unroll
        for (int k = 0; k < EDGED; ++k) {
            float tk = vsh[k];
#pragma unroll
            for (int j = 0; j < EDGED; ++j) tk = fmaf(Msh[k * 16 + j], ash[j], tk);
            q = fmaf(ash[k], tk, q);
        }
        float inv = rsqrtf(q * (1.f / HD) + LN_EPS);
        float y = 0.f;
#pragma unroll
        for (int k = 0; k < EDGED; ++k) y = fmaf(Wp[t * EDGED + k], ash[k], y);
        slv3[l * HD + t] = fmaxf(fmaf(fmaf(y, g[t], bg3[l * HD + t]), inv, edge_be[l * HD + t]), 0.f);
    }
}

// Per CSR slot: gather attr row once; emit PACKED meta per layer:
// low 16 bits = src node id (N < 65536), high 16 bits = fp16 inv-std.
// Also emits the attr row PERMUTED into slot order as fp16 (attr16).
__launch_bounds__(256)
__global__ void einv_k(const int2* __restrict__ es, const float* __restrict__ eattr,
                       const float* __restrict__ M3, const float* __restrict__ v3,
                       const float* __restrict__ s03, unsigned* __restrict__ sei,
                       _Float16* __restrict__ attr16, int E)
{
    __shared__ float Ms[3 * 256];
    __shared__ float vs[3 * 16];
    __shared__ float s0s[4];
    const int t = threadIdx.x;
    for (int i = t; i < 768; i += 256) Ms[i] = M3[i];
    if (t < 48) vs[t] = v3[t];
    if (t < 3) s0s[t] = s03[t];
    __syncthreads();
    int slot = blockIdx.x * 256 + t;
    if (slot >= E) return;
    int2 se = es[slot];
    const float4* ap = (const float4*)(eattr + (size_t)se.y * EDGED);
    float4 A0 = ap[0], A1 = ap[1], A2 = ap[2], A3 = ap[3];
    float a[16] = {A0.x, A0.y, A0.z, A0.w, A1.x, A1.y, A1.z, A1.w,
                   A2.x, A2.y, A2.z, A2.w, A3.x, A3.y, A3.z, A3.w};
    {
        half8v o0, o1;
#pragma unroll
        for (int i = 0; i < 8; ++i) { o0[i] = (_Float16)a[i]; o1[i] = (_Float16)a[8 + i]; }
        _Float16* op = attr16 + (size_t)slot * EDGED;
        *(half8v*)&op[0] = o0;
        *(half8v*)&op[8] = o1;
    }
#pragma unroll
    for (int l = 0; l < 3; ++l) {
        float q = s0s[l];
#pragma unroll
        for (int k = 0; k < 16; ++k) {
            const float* Mr = &Ms[l * 256 + k * 16];
            float tk = vs[l * 16 + k];
#pragma unroll
            for (int j = 0; j < 16; ++j) tk = fmaf(Mr[j], a[j], tk);
            q = fmaf(a[k], tk, q);
        }
        float iv = rsqrtf(q * (1.f / HD) + LN_EPS);
        union { _Float16 h; unsigned short u; } cv;
        cv.h = (_Float16)iv;
        sei[(size_t)l * E + slot] = ((unsigned)se.x & 0xFFFFu) | ((unsigned)cv.u << 16);
    }
}

// ---------------- MFMA GEMM v3 ---------------------------------------------
// AMODE 0: A bf16 hi/lo + W bf16 hi/lo (3 MFMA, ~fp32 accuracy)
// AMODE 1: A fp16 single + W fp16 hi/lo (2 MFMA f16)
// OUTMODE 0: fp32 C; 2: fp16 single (Co1)
template<int K, int NC, int ACT, int STATS, int AMODE, int OUTMODE>
__launch_bounds__(256)
__global__ void mgemm_k(const void* __restrict__ Ap1, const void* __restrict__ Ap2,
                        const void* __restrict__ Wp1, const void* __restrict__ Wp2,
                        const float* __restrict__ bias, float* __restrict__ C,
                        void* __restrict__ Co1, int M, float* __restrict__ stats)
{
    constexpr int RG = 2;
    constexpr int NT = 4;
    constexpr int NK = K / 32;
    __shared__ float st_lds[2][64];

    const int t    = threadIdx.x;
    const int lane = t & 63;
    const int wv   = t >> 6;
    const int ln15 = lane & 15;
    const int quad = lane >> 4;
    const int row_base = blockIdx.x * 128 + wv * 32;
    const int col0 = blockIdx.y * 64;

    f32x4 acc[RG][NT];
#pragma unroll
    for (int g = 0; g < RG; ++g)
#pragma unroll
        for (int nt = 0; nt < NT; ++nt)
#pragma unroll
            for (int r = 0; r < 4; ++r) acc[g][nt][r] = 0.f;

    size_t arow[RG];
#pragma unroll
    for (int g = 0; g < RG; ++g) {
        int row = row_base + g * 16 + ln15;
        row = row < M ? row : M - 1;          // clamp: junk values, store masked
        arow[g] = (size_t)row * K + quad * 8;
    }
    size_t brow[NT];
#pragma unroll
    for (int nt = 0; nt < NT; ++nt)
        brow[nt] = (size_t)(col0 + nt * 16 + ln15) * K + quad * 8;

    if constexpr (AMODE == 0) {
        const __bf16* Ahi = (const __bf16*)Ap1;
        const __bf16* Alo = (const __bf16*)Ap2;
        const __bf16* Whi = (const __bf16*)Wp1;
        const __bf16* Wlo = (const __bf16*)Wp2;
        bf16x8 a0h[RG], a0l[RG], a1h[RG], a1l[RG];
        bf16x8 b0h[NT], b0l[NT], b1h[NT], b1l[NT];

#define LD_A(kc, AH, AL) { \
    _Pragma("unroll") \
    for (int g = 0; g < RG; ++g) { \
        AH[g] = *(const bf16x8*)(Ahi + arow[g] + (kc)); \
        AL[g] = *(const bf16x8*)(Alo + arow[g] + (kc)); \
    } }
#define LD_B(kc, BH, BL) { \
    _Pragma("unroll") \
    for (int nt = 0; nt < NT; ++nt) { \
        BH[nt] = *(const bf16x8*)(Whi + brow[nt] + (kc)); \
        BL[nt] = *(const bf16x8*)(Wlo + brow[nt] + (kc)); \
    } }
#define DO_MFMA(AH, AL, BH, BL) { \
    _Pragma("unroll") \
    for (int nt = 0; nt < NT; ++nt) { \
        _Pragma("unroll") \
        for (int g = 0; g < RG; ++g) { \
            acc[g][nt] = __builtin_amdgcn_mfma_f32_16x16x32_bf16(AH[g], BH[nt], acc[g][nt], 0, 0, 0); \
            acc[g][nt] = __builtin_amdgcn_mfma_f32_16x16x32_bf16(AH[g], BL[nt], acc[g][nt], 0, 0, 0); \
            acc[g][nt] = __builtin_amdgcn_mfma_f32_16x16x32_bf16(AL[g], BH[nt], acc[g][nt], 0, 0, 0); \
        } } }

        LD_A(0, a0h, a0l);
        LD_B(0, b0h, b0l);
        for (int s = 0; s < NK; s += 2) {
            LD_A((s + 1) * 32, a1h, a1l);
            LD_B((s + 1) * 32, b1h, b1l);
            DO_MFMA(a0h, a0l, b0h, b0l);
            if (s + 2 < NK) {
                LD_A((s + 2) * 32, a0h, a0l);
                LD_B((s + 2) * 32, b0h, b0l);
            }
            DO_MFMA(a1h, a1l, b1h, b1l);
        }
#undef LD_A
#undef LD_B
#undef DO_MFMA
    } else {
        const _Float16* Af = (const _Float16*)Ap1;
        const _Float16* Wh = (const _Float16*)Wp1;
        const _Float16* Wl = (const _Float16*)Wp2;
        half8v a0[RG], a1[RG];
        half8v b0h[NT], b0l[NT], b1h[NT], b1l[NT];

#define LD_A16(kc, A) { \
    _Pragma("unroll") \
    for (int g = 0; g < RG; ++g) A[g] = *(const half8v*)(Af + arow[g] + (kc)); }
#define LD_B16(kc, BH, BL) { \
    _Pragma("unroll") \
    for (int nt = 0; nt < NT; ++nt) { \
        BH[nt] = *(const half8v*)(Wh + brow[nt] + (kc)); \
        BL[nt] = *(const half8v*)(Wl + brow[nt] + (kc)); \
    } }
#define DO_MFMA16(A, BH, BL) { \
    _Pragma("unroll") \
    for (int nt = 0; nt < NT; ++nt) { \
        _Pragma("unroll") \
        for (int g = 0; g < RG; ++g) { \
            acc[g][nt] = __builtin_amdgcn_mfma_f32_16x16x32_f16(A[g], BH[nt], acc[g][nt], 0, 0, 0); \
            acc[g][nt] = __builtin_amdgcn_mfma_f32_16x16x32_f16(A[g], BL[nt], acc[g][nt], 0, 0, 0); \
        } } }

        LD_A16(0, a0);
        LD_B16(0, b0h, b0l);
        for (int s = 0; s < NK; s += 2) {
            LD_A16((s + 1) * 32, a1);
            LD_B16((s + 1) * 32, b1h, b1l);
            DO_MFMA16(a0, b0h, b0l);
            if (s + 2 < NK) {
                LD_A16((s + 2) * 32, a0);
                LD_B16((s + 2) * 32, b0h, b0l);
            }
            DO_MFMA16(a1, b1h, b1l);
        }
#undef LD_A16
#undef LD_B16
#undef DO_MFMA16
    }

    if (STATS) {
        if (t < 64) { st_lds[0][t] = 0.f; st_lds[1][t] = 0.f; }
        __syncthreads();
    }

    float bv[NT];
#pragma unroll
    for (int nt = 0; nt < NT; ++nt) bv[nt] = bias[col0 + nt * 16 + ln15];

    float s1[NT], s2[NT];
#pragma unroll
    for (int nt = 0; nt < NT; ++nt) { s1[nt] = 0.f; s2[nt] = 0.f; }

#pragma unroll
    for (int g = 0; g < RG; ++g)
#pragma unroll
        for (int r = 0; r < 4; ++r) {
            int row = row_base + g * 16 + quad * 4 + r;
            if (row < M) {
#pragma unroll
                for (int nt = 0; nt < NT; ++nt) {
                    float v = acc[g][nt][r] + bv[nt];
                    if (ACT == 1) v = gelu_exact(v);
                    size_t ci = (size_t)row * NC + col0 + nt * 16 + ln15;
                    if (OUTMODE == 2) {
                        ((_Float16*)Co1)[ci] = (_Float16)v;
                    } else {
                        C[ci] = v;
                    }
                    if (STATS) { s1[nt] += v; s2[nt] += v * v; }
                }
            }
        }

    if (STATS) {
#pragma unroll
        for (int nt = 0; nt < NT; ++nt) {
            atomicAdd(&st_lds[0][nt * 16 + ln15], s1[nt]);
            atomicAdd(&st_lds[1][nt * 16 + ln15], s2[nt]);
        }
        __syncthreads();
        if (t < 64) {
            atomicAdd(&stats[col0 + t],      st_lds[0][t]);
            atomicAdd(&stats[HD + col0 + t], st_lds[1][t]);
        }
    }
}

// ---------------- fused node-embed: GEMM(K=64) + LayerNorm + ReLU -> fp16 --
__launch_bounds__(256)
__global__ void nemb_k(const __bf16* __restrict__ Ahi, const __bf16* __restrict__ Alo,
                       const __bf16* __restrict__ Whi, const __bf16* __restrict__ Wlo,
                       const float* __restrict__ bias, const float* __restrict__ gam,
                       const float* __restrict__ bet, _Float16* __restrict__ h16, int M)
{
    constexpr int RG = 2;
    constexpr int NT = 8;
    const int t    = threadIdx.x;
    const int lane = t & 63;
    const int wv   = t >> 6;
    const int ln15 = lane & 15;
    const int quad = lane >> 4;
    const int row_base = blockIdx.x * 128 + wv * 32;

    f32x4 acc[RG][NT];
#pragma unroll
    for (int g = 0; g < RG; ++g)
#pragma unroll
        for (int nt = 0; nt < NT; ++nt)
#pragma unroll
            for (int r = 0; r < 4; ++r) acc[g][nt][r] = 0.f;

    size_t arow[RG];
#pragma unroll
    for (int g = 0; g < RG; ++g) {
        int row = row_base + g * 16 + ln15;
        row = row < M ? row : M - 1;
        arow[g] = (size_t)row * NODED + quad * 8;
    }
    size_t brow[NT];
#pragma unroll
    for (int nt = 0; nt < NT; ++nt)
        brow[nt] = (size_t)(nt * 16 + ln15) * NODED + quad * 8;

#pragma unroll
    for (int s = 0; s < 2; ++s) {
        bf16x8 ah[RG], al[RG];
#pragma unroll
        for (int g = 0; g < RG; ++g) {
            ah[g] = *(const bf16x8*)(Ahi + arow[g] + s * 32);
            al[g] = *(const bf16x8*)(Alo + arow[g] + s * 32);
        }
#pragma unroll
        for (int nt = 0; nt < NT; ++nt) {
            bf16x8 bh = *(const bf16x8*)(Whi + brow[nt] + s * 32);
            bf16x8 bl = *(const bf16x8*)(Wlo + brow[nt] + s * 32);
#pragma unroll
            for (int g = 0; g < RG; ++g) {
                acc[g][nt] = __builtin_amdgcn_mfma_f32_16x16x32_bf16(ah[g], bh, acc[g][nt], 0, 0, 0);
                acc[g][nt] = __builtin_amdgcn_mfma_f32_16x16x32_bf16(ah[g], bl, acc[g][nt], 0, 0, 0);
                acc[g][nt] = __builtin_amdgcn_mfma_f32_16x16x32_bf16(al[g], bh, acc[g][nt], 0, 0, 0);
            }
        }
    }

    float bv[NT], gv[NT], betv[NT];
#pragma unroll
    for (int nt = 0; nt < NT; ++nt) {
        int col = nt * 16 + ln15;
        bv[nt]   = bias[col];
        gv[nt]   = gam[col];
        betv[nt] = bet[col];
    }

#pragma unroll
    for (int g = 0; g < RG; ++g)
#pragma unroll
        for (int r = 0; r < 4; ++r) {
            int row = row_base + g * 16 + quad * 4 + r;
            float v[NT];
            float s = 0.f, q = 0.f;
#pragma unroll
            for (int nt = 0; nt < NT; ++nt) {
                v[nt] = acc[g][nt][r] + bv[nt];
                s += v[nt];
                q += v[nt] * v[nt];
            }
#pragma unroll
            for (int o = 8; o > 0; o >>= 1) {
                s += __shfl_xor(s, o, 64);
                q += __shfl_xor(q, o, 64);
            }
            float mu  = s * (1.f / 128.f);
            float inv = rsqrtf(q * (1.f / 128.f) - mu * mu + LN_EPS);
            if (row < M) {
#pragma unroll
                for (int nt = 0; nt < NT; ++nt) {
                    float rr = fmaxf(fmaf((v[nt] - mu) * inv, gv[nt], betv[nt]), 0.f);
                    h16[(size_t)row * HD + nt * 16 + ln15] = (_Float16)rr;
                }
            }
        }
}

// ---------------- pull aggregation v10: no LDS staging ---------------------
// attr16 rows are consumed wave-uniformly (every lane needs the same row per
// edge), so the LDS round-trip (stage + lgkmcnt(0) drain + 2 ds_read/edge) is
// pure overhead: read attrs directly from global as broadcast loads (one
// request/wave, L1/L2-fed, stream is contiguous). Meta stays chunk-loaded
// lane-parallel + shfl (prefetch depth for the h-gather chain). Zero LDS.
__launch_bounds__(256)
__global__ void pull10_k(const _Float16* __restrict__ h16, const int* __restrict__ rs,
                         const _Float16* __restrict__ attr16, const unsigned* __restrict__ sei,
                         const float* __restrict__ slv, const _Float16* __restrict__ Wg16,
                         const float* __restrict__ bg, const float* __restrict__ bet,
                         __bf16* __restrict__ Ahi, __bf16* __restrict__ Alo, int N)
{
    const int t = threadIdx.x;
    const int lane = t & 63;
    const int wv = t >> 6;

    const int c0 = lane * 2;
    half2v w0p[8], w1p[8];
#pragma unroll
    for (int k = 0; k < 8; ++k) {
        w0p[k] = *(const half2v*)&Wg16[c0 * EDGED + 2 * k];
        w1p[k] = *(const half2v*)&Wg16[(c0 + 1) * EDGED + 2 * k];
    }
    const float2 bgv  = *(const float2*)&bg[c0];
    const float2 btv  = *(const float2*)&bet[c0];
    const float2 slvv = *(const float2*)&slv[c0];

    const int stride = gridDim.x << 2;
    for (int n = (blockIdx.x << 2) + wv; n < N; n += stride) {
        half2v hs = *(const half2v*)&h16[(size_t)n * HD + c0];
        float acc0 = (float)hs.x + slvv.x;
        float acc1 = (float)hs.y + slvv.y;

        const int beg = rs[n], end = rs[n + 1];
        for (int s0 = beg; s0 < end; s0 += 64) {
            int m = end - s0; if (m > 64) m = 64;
            int sv = 0;
            if (lane < m) sv = (int)sei[s0 + lane];

#define EDGE_BODY(A0V, A1V, IVJ, HVJ) { \
            HU ua, ub; \
            ua.v = A0V; \
            ub.v = A1V; \
            float p0 = bgv.x, q0 = 0.f, p1 = bgv.y, q1 = 0.f; \
            p0 = __builtin_amdgcn_fdot2(ua.p[0], w0p[0], p0, false); \
            q0 = __builtin_amdgcn_fdot2(ua.p[1], w0p[1], q0, false); \
            p1 = __builtin_amdgcn_fdot2(ua.p[0], w1p[0], p1, false); \
            q1 = __builtin_amdgcn_fdot2(ua.p[1], w1p[1], q1, false); \
            p0 = __builtin_amdgcn_fdot2(ua.p[2], w0p[2], p0, false); \
            q0 = __builtin_amdgcn_fdot2(ua.p[3], w0p[3], q0, false); \
            p1 = __builtin_amdgcn_fdot2(ua.p[2], w1p[2], p1, false); \
            q1 = __builtin_amdgcn_fdot2(ua.p[3], w1p[3], q1, false); \
            p0 = __builtin_amdgcn_fdot2(ub.p[0], w0p[4], p0, false); \
            q0 = __builtin_amdgcn_fdot2(ub.p[1], w0p[5], q0, false); \
            p1 = __builtin_amdgcn_fdot2(ub.p[0], w1p[4], p1, false); \
            q1 = __builtin_amdgcn_fdot2(ub.p[1], w1p[5], q1, false); \
            p0 = __builtin_amdgcn_fdot2(ub.p[2], w0p[6], p0, false); \
            q0 = __builtin_amdgcn_fdot2(ub.p[3], w0p[7], q0, false); \
            p1 = __builtin_amdgcn_fdot2(ub.p[2], w1p[6], p1, false); \
            q1 = __builtin_amdgcn_fdot2(ub.p[3], w1p[7], q1, false); \
            acc0 += fmaxf(fmaf(p0 + q0, IVJ, btv.x), 0.f) + (float)HVJ.x; \
            acc1 += fmaxf(fmaf(p1 + q1, IVJ, btv.y), 0.f) + (float)HVJ.y; \
        }

            int j = 0;
            for (; j + 4 <= m; j += 4) {
                int v0 = __shfl(sv, j,     64);
                int v1 = __shfl(sv, j + 1, 64);
                int v2 = __shfl(sv, j + 2, 64);
                int v3 = __shfl(sv, j + 3, 64);
                // attrs: wave-uniform addresses -> broadcast loads, contiguous stream
                const half8v* ap = (const half8v*)&attr16[(size_t)(s0 + j) * EDGED];
                half8v a00 = ap[0], a01 = ap[1];
                half8v a10 = ap[2], a11 = ap[3];
                half8v a20 = ap[4], a21 = ap[5];
                half8v a30 = ap[6], a31 = ap[7];
                int s_0 = v0 & 0xFFFF, s_1 = v1 & 0xFFFF;
                int s_2 = v2 & 0xFFFF, s_3 = v3 & 0xFFFF;
                float i0 = hi16_to_f(v0);
                float i1 = hi16_to_f(v1);
                float i2 = hi16_to_f(v2);
                float i3 = hi16_to_f(v3);
                half2v h0 = *(const half2v*)&h16[(size_t)s_0 * HD + c0];
                half2v h1 = *(const half2v*)&h16[(size_t)s_1 * HD + c0];
                half2v h2 = *(const half2v*)&h16[(size_t)s_2 * HD + c0];
                half2v h3 = *(const half2v*)&h16[(size_t)s_3 * HD + c0];
                EDGE_BODY(a00, a01, i0, h0);
                EDGE_BODY(a10, a11, i1, h1);
                EDGE_BODY(a20, a21, i2, h2);
                EDGE_BODY(a30, a31, i3, h3);
            }
            for (; j < m; ++j) {
                int vj = __shfl(sv, j, 64);
                const half8v* ap = (const half8v*)&attr16[(size_t)(s0 + j) * EDGED];
                half8v a00 = ap[0], a01 = ap[1];
                int s_ = vj & 0xFFFF;
                float ij = hi16_to_f(vj);
                half2v hj = *(const half2v*)&h16[(size_t)s_ * HD + c0];
                EDGE_BODY(a00, a01, ij, hj);
            }
#undef EDGE_BODY
        }
        __bf16 b0 = (__bf16)acc0, b1 = (__bf16)acc1;
        union { __bf16 b[2]; unsigned u; } ph, pl;
        ph.b[0] = b0;
        ph.b[1] = b1;
        pl.b[0] = (__bf16)(acc0 - (float)b0);
        pl.b[1] = (__bf16)(acc1 - (float)b1);
        *(unsigned*)&Ahi[(size_t)n * HD + c0] = ph.u;
        *(unsigned*)&Alo[(size_t)n * HD + c0] = pl.u;
    }
}

// BatchNorm apply from accumulated column sums; input fp16, optional ReLU.
// out16 != null -> write fp16 (h for next layer); else fp32 to out32.
__global__ void bn_k(const _Float16* __restrict__ hl, const float* __restrict__ stats,
                     const float* __restrict__ gam, const float* __restrict__ bet,
                     float* __restrict__ out32, _Float16* __restrict__ out16,
                     int total4, float invN, int relu)
{
    int idx = blockIdx.x * blockDim.x + threadIdx.x;
    if (idx < total4) {
        int c4 = idx & 31;
        half4v xh = *(const half4v*)&hl[(size_t)idx * 4];
        float4 s1 = ((const float4*)stats)[c4];
        float4 s2 = ((const float4*)stats)[32 + c4];
        float4 g  = ((const float4*)gam)[c4];
        float4 b  = ((const float4*)bet)[c4];
        float4 r;
        {
            float m = s1.x * invN; float v = s2.x * invN - m * m;
            r.x = fmaf(((float)xh.x - m) * rsqrtf(v + LN_EPS), g.x, b.x);
        }
        {
            float m = s1.y * invN; float v = s2.y * invN - m * m;
            r.y = fmaf(((float)xh.y - m) * rsqrtf(v + LN_EPS), g.y, b.y);
        }
        {
            float m = s1.z * invN; float v = s2.z * invN - m * m;
            r.z = fmaf(((float)xh.z - m) * rsqrtf(v + LN_EPS), g.z, b.z);
        }
        {
            float m = s1.w * invN; float v = s2.w * invN - m * m;
            r.w = fmaf(((float)xh.w - m) * rsqrtf(v + LN_EPS), g.w, b.w);
        }
        if (relu) {
            r.x = fmaxf(r.x, 0.f); r.y = fmaxf(r.y, 0.f);
            r.z = fmaxf(r.z, 0.f); r.w = fmaxf(r.w, 0.f);
        }
        if (out16) {
            half4v o;
            o.x = (_Float16)r.x; o.y = (_Float16)r.y;
            o.z = (_Float16)r.z; o.w = (_Float16)r.w;
            *(half4v*)&out16[(size_t)idx * 4] = o;
        } else {
            ((float4*)out32)[idx] = r;
        }
    }
}

extern "C" void kernel_launch(void* const* d_in, const int* in_sizes, int n_in,
                              void* d_out, int out_size, void* d_ws, size_t ws_size,
                              hipStream_t stream)
{
    const float* x       = (const float*)d_in[0];
    const int*   ei      = (const int*)d_in[1];
    const float* eattr   = (const float*)d_in[2];
    const float* node_W  = (const float*)d_in[3];
    const float* node_b  = (const float*)d_in[4];
    const float* node_g  = (const float*)d_in[5];
    const float* node_be = (const float*)d_in[6];
    const float* edge_W  = (const float*)d_in[7];
    const float* edge_b  = (const float*)d_in[8];
    const float* edge_g  = (const float*)d_in[9];
    const float* edge_be = (const float*)d_in[10];
    const float* sl_attr = (const float*)d_in[11];
    const float* W1      = (const float*)d_in[12];
    const float* b1      = (const float*)d_in[13];
    const float* W2      = (const float*)d_in[14];
    const float* b2      = (const float*)d_in[15];
    const float* bn_g    = (const float*)d_in[16];
    const float* bn_b    = (const float*)d_in[17];

    const int N = in_sizes[0] / NODED;
    const int E = in_sizes[1] / 2;

    // explicit 16B-aligned workspace layout
    char* base = (char*)d_ws;
    size_t off = 0;
    auto take = [&](size_t nbytes) -> void* {
        void* p = base + off;
        off = (off + nbytes + 15) & ~(size_t)15;
        return p;
    };
    _Float16* h16  = (_Float16*)take((size_t)N * HD * 2); // node features (fp16)
    _Float16* hl16 = (_Float16*)take((size_t)N * HD * 2); // mlp2 out (pre-BN, fp16)
    __bf16* aghi   = (__bf16*)take((size_t)N * HD * 2);    // aggr bf16 hi
    __bf16* aglo   = (__bf16*)take((size_t)N * HD * 2);
    _Float16* z16  = (_Float16*)take((size_t)N * 256 * 2); // mlp1 out fp16
    __bf16* xhi    = (__bf16*)take((size_t)N * NODED * 2);
    __bf16* xlo    = (__bf16*)take((size_t)N * NODED * 2);
    float*  slv3   = (float*)take(3 * HD * 4);
    float*  stats  = (float*)take(3 * 256 * 4);
    int*    cnt    = (int*)take((size_t)N * 4);
    int*    cursor = (int*)take((size_t)N * 4);
    int*    bsum   = (int*)take(256 * 4);
    int*    boff   = (int*)take(256 * 4);
    int*    rs     = (int*)take(((size_t)N + 2) * 4);
    int2*   es     = (int2*)take((size_t)E * 8);
    unsigned* sei  = (unsigned*)take((size_t)3 * E * 4);   // packed (src16, iv-fp16)
    _Float16* attr16 = (_Float16*)take((size_t)E * EDGED * 2); // slot-permuted fp16 attrs
    _Float16* Wg16_3 = (_Float16*)take(3 * 2048 * 2);      // fp16 edge weights [c][k]
    float*  bg3    = (float*)take(3 * HD * 4);
    float*  M3     = (float*)take(3 * 256 * 4);
    float*  v3     = (float*)take(3 * 16 * 4);
    float*  s03    = (float*)take(4 * 4);
    __bf16* nWhi   = (__bf16*)take((size_t)HD * NODED * 2);
    __bf16* nWlo   = (__bf16*)take((size_t)HD * NODED * 2);
    __bf16* W1hi   = (__bf16*)take((size_t)3 * 256 * HD * 2);
    __bf16* W1lo   = (__bf16*)take((size_t)3 * 256 * HD * 2);
    _Float16* W2h16 = (_Float16*)take((size_t)3 * HD * 256 * 2);
    _Float16* W2l16 = (_Float16*)take((size_t)3 * HD * 256 * 2);

    // weight splits: node/W1 bf16 hi/lo, W2 fp16 hi/lo, x bf16 hi/lo
    wconv_k<<<(HD * NODED + 255) / 256, 256, 0, stream>>>(node_W, nWhi, nWlo, HD * NODED);
    wconv_k<<<(3 * 256 * HD + 255) / 256, 256, 0, stream>>>(W1, W1hi, W1lo, 3 * 256 * HD);
    wconv16_k<<<(3 * 256 * HD + 255) / 256, 256, 0, stream>>>(W2, W2h16, W2l16, 3 * 256 * HD);
    wconv_k<<<((int)((size_t)N * NODED + 255) / 256), 256, 0, stream>>>(x, xhi, xlo, N * NODED);

    // edge-LN precompute + self-loop embed + fp16 weights (all 3 layers)
    prep_k<<<3, 256, 0, stream>>>(edge_W, edge_b, edge_g, edge_be, sl_attr,
                                  Wg16_3, bg3, M3, v3, s03, slv3);

    // ---- CSR build ----
    const int eblocks = (E + 255) / 256;
    const int nblocks = (N + 255) / 256;
    hipMemsetAsync(cnt, 0, (size_t)N * sizeof(int), stream);
    hist_k<<<eblocks, 256, 0, stream>>>(ei, cnt, E);
    scan1_k<<<nblocks, 256, 0, stream>>>(cnt, rs, bsum, N);
    scan2_k<<<1, 256, 0, stream>>>(bsum, boff, nblocks);
    scan3_k<<<nblocks, 256, 0, stream>>>(rs, cursor, boff, N, E);
    scatter_k<<<eblocks, 256, 0, stream>>>(ei, cursor, es, E);

    // per-slot packed (src, iv) for all 3 layers + permuted fp16 attr stream
    einv_k<<<eblocks, 256, 0, stream>>>(es, eattr, M3, v3, s03, sei, attr16, E);

    const int total4  = N * (HD / 4);
    const int vblocks = (total4 + 255) / 256;
    const int gb128   = (N + 127) / 128;
    int pgrid = (N + 3) / 4;
    if (pgrid > 2048) pgrid = 2048;           // persistent: 8192 waves

    // node embed: fused Linear (MFMA) + LN + ReLU -> fp16 h
    nemb_k<<<gb128, 256, 0, stream>>>(xhi, xlo, nWhi, nWlo, node_b,
                                      node_g, node_be, h16, N);

    hipMemsetAsync(stats, 0, 3 * 256 * sizeof(float), stream);

    for (int l = 0; l < 3; ++l) {
        pull10_k<<<pgrid, 256, 0, stream>>>(h16, rs, attr16, sei + (size_t)l * E,
                                            slv3 + l * HD, Wg16_3 + (size_t)l * 2048,
                                            bg3 + l * HD, edge_be + l * HD,
                                            aghi, aglo, N);

        // mlp1: bf16 hi/lo A x bf16 hi/lo W -> gelu -> fp16 z
        mgemm_k<HD, 256, 1, 0, 0, 2><<<dim3(gb128, 4), 256, 0, stream>>>(
            aghi, aglo, W1hi + (size_t)l * 256 * HD, W1lo + (size_t)l * 256 * HD,
            b1 + l * 256, nullptr, z16, N, nullptr);

        // mlp2: fp16 A x fp16 hi/lo W -> fp16 hl + fp32 stats
        mgemm_k<256, HD, 0, 1, 1, 2><<<dim3(gb128, 2), 256, 0, stream>>>(
            z16, nullptr, W2h16 + (size_t)l * HD * 256, W2l16 + (size_t)l * HD * 256,
            b2 + l * HD, nullptr, hl16, N, stats + l * 256);

        bn_k<<<vblocks, 256, 0, stream>>>(hl16, stats + l * 256,
                                          bn_g + l * HD, bn_b + l * HD,
                                          (float*)d_out, (l < 2) ? h16 : nullptr,
                                          total4, 1.f / N, (l < 2) ? 1 : 0);
    }
}

// Round 10
// 832.015 us; speedup vs baseline: 1.0710x; 1.0710x over previous
//
#include <hip/hip_runtime.h>
#include <cstdint>
#include <cstddef>

#define HD 128
#define EDGED 16
#define NODED 64
#define LN_EPS 1e-5f

typedef __bf16 bf16x8 __attribute__((ext_vector_type(8)));
typedef float  f32x4  __attribute__((ext_vector_type(4)));
typedef _Float16 half2v __attribute__((ext_vector_type(2)));
typedef _Float16 half4v __attribute__((ext_vector_type(4)));
typedef _Float16 half8v __attribute__((ext_vector_type(8)));

union HU { half8v v; half2v p[4]; };

__device__ __forceinline__ float gelu_exact(float x) {
    return 0.5f * x * (1.0f + erff(x * 0.7071067811865475f));
}

__device__ __forceinline__ float hi16_to_f(int bits) {
    union { unsigned short u; _Float16 h; } c;
    c.u = (unsigned short)((unsigned)bits >> 16);
    return (float)c.h;
}

// fp32 -> bf16 hi/lo split (a ~= hi + lo, lo captures the rounding residual)
__global__ void wconv_k(const float* __restrict__ in, __bf16* __restrict__ hi,
                        __bf16* __restrict__ lo, int n) {
    int i = blockIdx.x * blockDim.x + threadIdx.x;
    if (i < n) {
        float v = in[i];
        __bf16 h = (__bf16)v;
        hi[i] = h;
        lo[i] = (__bf16)(v - (float)h);
    }
}

// fp32 -> fp16 hi/lo split
__global__ void wconv16_k(const float* __restrict__ in, _Float16* __restrict__ hi,
                          _Float16* __restrict__ lo, int n) {
    int i = blockIdx.x * blockDim.x + threadIdx.x;
    if (i < n) {
        float v = in[i];
        _Float16 h = (_Float16)v;
        hi[i] = h;
        lo[i] = (_Float16)(v - (float)h);
    }
}

// ---------------- CSR build ----------------

__global__ void hist_k(const int* __restrict__ ei, int* __restrict__ cnt, int E) {
    int e = blockIdx.x * blockDim.x + threadIdx.x;
    if (e < E) atomicAdd(&cnt[ei[E + e]], 1);
}

__global__ void scan1_k(const int* __restrict__ in, int* __restrict__ out,
                        int* __restrict__ bsum, int n) {
    __shared__ int lds[256];
    int t = threadIdx.x;
    int i = blockIdx.x * 256 + t;
    int v = (i < n) ? in[i] : 0;
    lds[t] = v;
    __syncthreads();
#pragma unroll
    for (int o = 1; o < 256; o <<= 1) {
        int u = (t >= o) ? lds[t - o] : 0;
        __syncthreads();
        lds[t] += u;
        __syncthreads();
    }
    if (i < n) out[i] = lds[t] - v;
    if (t == 255) bsum[blockIdx.x] = lds[255];
}

__global__ void scan2_k(const int* __restrict__ bsum, int* __restrict__ boff, int nb) {
    __shared__ int lds[256];
    int t = threadIdx.x;
    int v = (t < nb) ? bsum[t] : 0;
    lds[t] = v;
    __syncthreads();
#pragma unroll
    for (int o = 1; o < 256; o <<= 1) {
        int u = (t >= o) ? lds[t - o] : 0;
        __syncthreads();
        lds[t] += u;
        __syncthreads();
    }
    if (t < nb) boff[t] = lds[t] - v;
}

// adds block offsets; also emits the scatter cursor copy (saves a d2d memcpy)
__global__ void scan3_k(int* __restrict__ rs, int* __restrict__ cursor,
                        const int* __restrict__ boff, int n, int E) {
    int i = blockIdx.x * 256 + threadIdx.x;
    if (i < n) {
        int v = rs[i] + boff[blockIdx.x];
        rs[i] = v;
        cursor[i] = v;
    }
    if (i == 0) rs[n] = E;
}

__global__ void scatter_k(const int* __restrict__ ei, int* __restrict__ cursor,
                          int2* __restrict__ es, int E) {
    int e = blockIdx.x * blockDim.x + threadIdx.x;
    if (e < E) {
        int dst = ei[E + e];
        int slot = atomicAdd(&cursor[dst], 1);
        es[slot] = make_int2(ei[e], e);
    }
}

// ---------------- edge-LN precompute (+ fused self-loop embed) ----------------
__global__ void prep_k(const float* __restrict__ edge_W, const float* __restrict__ edge_b,
                       const float* __restrict__ edge_g, const float* __restrict__ edge_be,
                       const float* __restrict__ sl_attr, _Float16* __restrict__ Wg16_3,
                       float* __restrict__ bg3, float* __restrict__ M3,
                       float* __restrict__ v3, float* __restrict__ s03,
                       float* __restrict__ slv3)
{
    const int l = blockIdx.x;
    const float* W = edge_W + (size_t)l * HD * EDGED;
    const float* b = edge_b + l * HD;
    const float* g = edge_g + l * HD;
    __shared__ float Wp[HD * EDGED];
    __shared__ float bp[HD];
    __shared__ float wm[EDGED];
    __shared__ float Msh[256];
    __shared__ float vsh[EDGED];
    __shared__ float ash[EDGED];
    __shared__ float bmS, s0sh;
    const int t = threadIdx.x;
#pragma unroll
    for (int m = 0; m < 8; ++m) Wp[m * 256 + t] = W[m * 256 + t];
    __syncthreads();
    if (t < EDGED) {
        float s = 0.f;
        for (int c = 0; c < HD; ++c) s += Wp[c * EDGED + t];
        wm[t] = s * (1.f / HD);
    } else if (t == EDGED) {
        float s = 0.f;
        for (int c = 0; c < HD; ++c) s += b[c];
        bmS = s * (1.f / HD);
    }
    __syncthreads();
    if (t < HD) bp[t] = b[t] - bmS;
    __syncthreads();
#pragma unroll
    for (int m = 0; m < 8; ++m) {
        int idx = m * 256 + t;
        int c = idx >> 4, k = idx & 15;
        float val = Wp[idx] - wm[k];
        Wp[idx] = val;
        Wg16_3[(size_t)l * 2048 + idx] = (_Float16)(val * g[c]);   // [c][k] layout
    }
    if (t < HD) bg3[l * HD + t] = bp[t] * g[t];
    __syncthreads();
    {
        int k = t >> 4, j = t & 15;
        float s = 0.f;
        for (int c = 0; c < HD; ++c) s += Wp[c * EDGED + k] * Wp[c * EDGED + j];
        Msh[t] = s;
        M3[l * 256 + t] = s;
    }
    if (t < EDGED) {
        float s = 0.f;
        for (int c = 0; c < HD; ++c) s += Wp[c * EDGED + t] * bp[c];
        vsh[t] = 2.f * s;
        v3[l * EDGED + t] = 2.f * s;
        ash[t] = sl_attr[l * EDGED + t];
    } else if (t == EDGED) {
        float s = 0.f;
        for (int c = 0; c < HD; ++c) s += bp[c] * bp[c];
        s0sh = s;
        s03[l] = s;
    }
    __syncthreads();
    // self-loop embed: out_c = ((Wp.a)*g + bg)*inv + bet, relu
    if (t < HD) {
        float q = s0sh;
#pragma unroll
        for (int k = 0; k < EDGED; ++k) {
            float tk = vsh[k];
#pragma unroll
            for (int j = 0; j < EDGED; ++j) tk = fmaf(Msh[k * 16 + j], ash[j], tk);
            q = fmaf(ash[k], tk, q);
        }
        float inv = rsqrtf(q * (1.f / HD) + LN_EPS);
        float y = 0.f;
#pragma unroll
        for (int k = 0; k < EDGED; ++k) y = fmaf(Wp[t * EDGED + k], ash[k], y);
        slv3[l * HD + t] = fmaxf(fmaf(fmaf(y, g[t], bg3[l * HD + t]), inv, edge_be[l * HD + t]), 0.f);
    }
}

// Per CSR slot: gather attr row once; emit PACKED meta per layer:
// low 16 bits = src node id (N < 65536), high 16 bits = fp16 inv-std.
// Also emits the attr row PERMUTED into slot order as fp16 (attr16).
__launch_bounds__(256)
__global__ void einv_k(const int2* __restrict__ es, const float* __restrict__ eattr,
                       const float* __restrict__ M3, const float* __restrict__ v3,
                       const float* __restrict__ s03, unsigned* __restrict__ sei,
                       _Float16* __restrict__ attr16, int E)
{
    __shared__ float Ms[3 * 256];
    __shared__ float vs[3 * 16];
    __shared__ float s0s[4];
    const int t = threadIdx.x;
    for (int i = t; i < 768; i += 256) Ms[i] = M3[i];
    if (t < 48) vs[t] = v3[t];
    if (t < 3) s0s[t] = s03[t];
    __syncthreads();
    int slot = blockIdx.x * 256 + t;
    if (slot >= E) return;
    int2 se = es[slot];
    const float4* ap = (const float4*)(eattr + (size_t)se.y * EDGED);
    float4 A0 = ap[0], A1 = ap[1], A2 = ap[2], A3 = ap[3];
    float a[16] = {A0.x, A0.y, A0.z, A0.w, A1.x, A1.y, A1.z, A1.w,
                   A2.x, A2.y, A2.z, A2.w, A3.x, A3.y, A3.z, A3.w};
    {
        half8v o0, o1;
#pragma unroll
        for (int i = 0; i < 8; ++i) { o0[i] = (_Float16)a[i]; o1[i] = (_Float16)a[8 + i]; }
        _Float16* op = attr16 + (size_t)slot * EDGED;
        *(half8v*)&op[0] = o0;
        *(half8v*)&op[8] = o1;
    }
#pragma unroll
    for (int l = 0; l < 3; ++l) {
        float q = s0s[l];
#pragma unroll
        for (int k = 0; k < 16; ++k) {
            const float* Mr = &Ms[l * 256 + k * 16];
            float tk = vs[l * 16 + k];
#pragma unroll
            for (int j = 0; j < 16; ++j) tk = fmaf(Mr[j], a[j], tk);
            q = fmaf(a[k], tk, q);
        }
        float iv = rsqrtf(q * (1.f / HD) + LN_EPS);
        union { _Float16 h; unsigned short u; } cv;
        cv.h = (_Float16)iv;
        sei[(size_t)l * E + slot] = ((unsigned)se.x & 0xFFFFu) | ((unsigned)cv.u << 16);
    }
}

// ---------------- fused MLP: mlp1(K=128,N=256,gelu) + mlp2(K=256,N=128) ----
// One block = 128 rows; each wave owns 32 rows END-TO-END (no barriers).
// Stage 1: z = gelu(A @ W1^T + b1) -> per-wave LDS tile (fp16, 16 KB/wave),
// two 128-col halves to bound VGPR. Stage 2: out = z @ W2^T + b2 from LDS
// (ds_read_b128 A-frags) with fp16-hi/lo W2; stats from fp32 pre-rounding.
// Kills the z16 global round-trip (51 MB/layer) and one launch per layer.
__launch_bounds__(256)
__global__ void fmlp_k(const __bf16* __restrict__ Ahi, const __bf16* __restrict__ Alo,
                       const __bf16* __restrict__ W1hi, const __bf16* __restrict__ W1lo,
                       const float* __restrict__ b1, const _Float16* __restrict__ W2h,
                       const _Float16* __restrict__ W2l, const float* __restrict__ b2,
                       _Float16* __restrict__ hl16, int M, float* __restrict__ stats)
{
    constexpr int RG = 2;
    constexpr int NT = 8;
    __shared__ _Float16 zlds_all[4][32 * 256];   // 64 KB: per-wave z tile
    __shared__ float st_lds[2][128];

    const int t    = threadIdx.x;
    const int lane = t & 63;
    const int wv   = t >> 6;
    const int ln15 = lane & 15;
    const int quad = lane >> 4;
    const int row_base = blockIdx.x * 128 + wv * 32;
    _Float16* zl = zlds_all[wv];

    size_t arow[RG];
#pragma unroll
    for (int g = 0; g < RG; ++g) {
        int row = row_base + g * 16 + ln15;
        row = row < M ? row : M - 1;          // clamp: junk values, stores masked
        arow[g] = (size_t)row * HD + quad * 8;
    }

    // ---- stage 1: two 128-col halves ----
#pragma unroll
    for (int h = 0; h < 2; ++h) {
        const int col0 = h * 128;
        f32x4 acc[RG][NT];
#pragma unroll
        for (int g = 0; g < RG; ++g)
#pragma unroll
            for (int nt = 0; nt < NT; ++nt)
#pragma unroll
                for (int r = 0; r < 4; ++r) acc[g][nt][r] = 0.f;

#pragma unroll
        for (int s = 0; s < 4; ++s) {        // K=128
            bf16x8 ah[RG], al[RG];
#pragma unroll
            for (int g = 0; g < RG; ++g) {
                ah[g] = *(const bf16x8*)(Ahi + arow[g] + s * 32);
                al[g] = *(const bf16x8*)(Alo + arow[g] + s * 32);
            }
#pragma unroll
            for (int nt = 0; nt < NT; ++nt) {
                size_t br = (size_t)(col0 + nt * 16 + ln15) * HD + quad * 8 + s * 32;
                bf16x8 bh = *(const bf16x8*)(W1hi + br);
                bf16x8 bl = *(const bf16x8*)(W1lo + br);
#pragma unroll
                for (int g = 0; g < RG; ++g) {
                    acc[g][nt] = __builtin_amdgcn_mfma_f32_16x16x32_bf16(ah[g], bh, acc[g][nt], 0, 0, 0);
                    acc[g][nt] = __builtin_amdgcn_mfma_f32_16x16x32_bf16(ah[g], bl, acc[g][nt], 0, 0, 0);
                    acc[g][nt] = __builtin_amdgcn_mfma_f32_16x16x32_bf16(al[g], bh, acc[g][nt], 0, 0, 0);
                }
            }
        }

#pragma unroll
        for (int g = 0; g < RG; ++g)
#pragma unroll
            for (int r = 0; r < 4; ++r) {
                int lr = g * 16 + quad * 4 + r;
#pragma unroll
                for (int nt = 0; nt < NT; ++nt) {
                    int col = col0 + nt * 16 + ln15;
                    float v = gelu_exact(acc[g][nt][r] + b1[col]);
                    zl[lr * 256 + col] = (_Float16)v;
                }
            }
    }

    // ---- stage 2: out = z @ W2^T (K=256, 128 cols) ----
    if (t < 128) { st_lds[0][t] = 0.f; st_lds[1][t] = 0.f; }
    __syncthreads();                          // stats init only

    f32x4 acc2[RG][NT];
#pragma unroll
    for (int g = 0; g < RG; ++g)
#pragma unroll
        for (int nt = 0; nt < NT; ++nt)
#pragma unroll
            for (int r = 0; r < 4; ++r) acc2[g][nt][r] = 0.f;

#pragma unroll
    for (int s = 0; s < 8; ++s) {            // K=256
        half8v az[RG];
#pragma unroll
        for (int g = 0; g < RG; ++g)
            az[g] = *(const half8v*)&zl[(g * 16 + ln15) * 256 + s * 32 + quad * 8];
#pragma unroll
        for (int nt = 0; nt < NT; ++nt) {
            size_t br = (size_t)(nt * 16 + ln15) * 256 + quad * 8 + s * 32;
            half8v wh = *(const half8v*)(W2h + br);
            half8v wl = *(const half8v*)(W2l + br);
#pragma unroll
            for (int g = 0; g < RG; ++g) {
                acc2[g][nt] = __builtin_amdgcn_mfma_f32_16x16x32_f16(az[g], wh, acc2[g][nt], 0, 0, 0);
                acc2[g][nt] = __builtin_amdgcn_mfma_f32_16x16x32_f16(az[g], wl, acc2[g][nt], 0, 0, 0);
            }
        }
    }

    float bv[NT], s1[NT], s2[NT];
#pragma unroll
    for (int nt = 0; nt < NT; ++nt) {
        bv[nt] = b2[nt * 16 + ln15];
        s1[nt] = 0.f; s2[nt] = 0.f;
    }

#pragma unroll
    for (int g = 0; g < RG; ++g)
#pragma unroll
        for (int r = 0; r < 4; ++r) {
            int row = row_base + g * 16 + quad * 4 + r;
            if (row < M) {
#pragma unroll
                for (int nt = 0; nt < NT; ++nt) {
                    float v = acc2[g][nt][r] + bv[nt];
                    hl16[(size_t)row * HD + nt * 16 + ln15] = (_Float16)v;
                    s1[nt] += v;
                    s2[nt] += v * v;
                }
            }
        }

#pragma unroll
    for (int nt = 0; nt < NT; ++nt) {
        atomicAdd(&st_lds[0][nt * 16 + ln15], s1[nt]);
        atomicAdd(&st_lds[1][nt * 16 + ln15], s2[nt]);
    }
    __syncthreads();
    if (t < 128) {
        atomicAdd(&stats[t],      st_lds[0][t]);
        atomicAdd(&stats[HD + t], st_lds[1][t]);
    }
}

// ---------------- fused node-embed: GEMM(K=64) + LayerNorm + ReLU -> fp16 --
__launch_bounds__(256)
__global__ void nemb_k(const __bf16* __restrict__ Ahi, const __bf16* __restrict__ Alo,
                       const __bf16* __restrict__ Whi, const __bf16* __restrict__ Wlo,
                       const float* __restrict__ bias, const float* __restrict__ gam,
                       const float* __restrict__ bet, _Float16* __restrict__ h16, int M)
{
    constexpr int RG = 2;
    constexpr int NT = 8;
    const int t    = threadIdx.x;
    const int lane = t & 63;
    const int wv   = t >> 6;
    const int ln15 = lane & 15;
    const int quad = lane >> 4;
    const int row_base = blockIdx.x * 128 + wv * 32;

    f32x4 acc[RG][NT];
#pragma unroll
    for (int g = 0; g < RG; ++g)
#pragma unroll
        for (int nt = 0; nt < NT; ++nt)
#pragma unroll
            for (int r = 0; r < 4; ++r) acc[g][nt][r] = 0.f;

    size_t arow[RG];
#pragma unroll
    for (int g = 0; g < RG; ++g) {
        int row = row_base + g * 16 + ln15;
        row = row < M ? row : M - 1;
        arow[g] = (size_t)row * NODED + quad * 8;
    }
    size_t brow[NT];
#pragma unroll
    for (int nt = 0; nt < NT; ++nt)
        brow[nt] = (size_t)(nt * 16 + ln15) * NODED + quad * 8;

#pragma unroll
    for (int s = 0; s < 2; ++s) {
        bf16x8 ah[RG], al[RG];
#pragma unroll
        for (int g = 0; g < RG; ++g) {
            ah[g] = *(const bf16x8*)(Ahi + arow[g] + s * 32);
            al[g] = *(const bf16x8*)(Alo + arow[g] + s * 32);
        }
#pragma unroll
        for (int nt = 0; nt < NT; ++nt) {
            bf16x8 bh = *(const bf16x8*)(Whi + brow[nt] + s * 32);
            bf16x8 bl = *(const bf16x8*)(Wlo + brow[nt] + s * 32);
#pragma unroll
            for (int g = 0; g < RG; ++g) {
                acc[g][nt] = __builtin_amdgcn_mfma_f32_16x16x32_bf16(ah[g], bh, acc[g][nt], 0, 0, 0);
                acc[g][nt] = __builtin_amdgcn_mfma_f32_16x16x32_bf16(ah[g], bl, acc[g][nt], 0, 0, 0);
                acc[g][nt] = __builtin_amdgcn_mfma_f32_16x16x32_bf16(al[g], bh, acc[g][nt], 0, 0, 0);
            }
        }
    }

    float bv[NT], gv[NT], betv[NT];
#pragma unroll
    for (int nt = 0; nt < NT; ++nt) {
        int col = nt * 16 + ln15;
        bv[nt]   = bias[col];
        gv[nt]   = gam[col];
        betv[nt] = bet[col];
    }

#pragma unroll
    for (int g = 0; g < RG; ++g)
#pragma unroll
        for (int r = 0; r < 4; ++r) {
            int row = row_base + g * 16 + quad * 4 + r;
            float v[NT];
            float s = 0.f, q = 0.f;
#pragma unroll
            for (int nt = 0; nt < NT; ++nt) {
                v[nt] = acc[g][nt][r] + bv[nt];
                s += v[nt];
                q += v[nt] * v[nt];
            }
#pragma unroll
            for (int o = 8; o > 0; o >>= 1) {
                s += __shfl_xor(s, o, 64);
                q += __shfl_xor(q, o, 64);
            }
            float mu  = s * (1.f / 128.f);
            float inv = rsqrtf(q * (1.f / 128.f) - mu * mu + LN_EPS);
            if (row < M) {
#pragma unroll
                for (int nt = 0; nt < NT; ++nt) {
                    float rr = fmaxf(fmaf((v[nt] - mu) * inv, gv[nt], betv[nt]), 0.f);
                    h16[(size_t)row * HD + nt * 16 + ln15] = (_Float16)rr;
                }
            }
        }
}

// ---------------- pull aggregation v9: packed meta + fdot2 (best known) ----
__launch_bounds__(256)
__global__ void pull9_k(const _Float16* __restrict__ h16, const int* __restrict__ rs,
                        const _Float16* __restrict__ attr16, const unsigned* __restrict__ sei,
                        const float* __restrict__ slv, const _Float16* __restrict__ Wg16,
                        const float* __restrict__ bg, const float* __restrict__ bet,
                        __bf16* __restrict__ Ahi, __bf16* __restrict__ Alo, int N)
{
    __shared__ _Float16 alds_all[4][64 * EDGED];   // 8 KB: per-wave attr staging
    const int t = threadIdx.x;
    const int lane = t & 63;
    const int wv = t >> 6;
    _Float16* alds = alds_all[wv];
    uint4* alds4 = (uint4*)alds;

    const int c0 = lane * 2;
    half2v w0p[8], w1p[8];
#pragma unroll
    for (int k = 0; k < 8; ++k) {
        w0p[k] = *(const half2v*)&Wg16[c0 * EDGED + 2 * k];
        w1p[k] = *(const half2v*)&Wg16[(c0 + 1) * EDGED + 2 * k];
    }
    const float2 bgv  = *(const float2*)&bg[c0];
    const float2 btv  = *(const float2*)&bet[c0];
    const float2 slvv = *(const float2*)&slv[c0];

    const int stride = gridDim.x << 2;
    for (int n = (blockIdx.x << 2) + wv; n < N; n += stride) {
        half2v hs = *(const half2v*)&h16[(size_t)n * HD + c0];
        float acc0 = (float)hs.x + slvv.x;
        float acc1 = (float)hs.y + slvv.y;

        const int beg = rs[n], end = rs[n + 1];
        for (int s0 = beg; s0 < end; s0 += 64) {
            int m = end - s0; if (m > 64) m = 64;
            int sv = 0;
            if (lane < m) sv = (int)sei[s0 + lane];
            // stage fp16 attrs: contiguous stream copy, 32B/edge
            const uint4* src4 = (const uint4*)(attr16 + (size_t)s0 * EDGED);
#pragma unroll
            for (int it = 0; it < 2; ++it) {
                int idx = (it << 6) + lane;
                if (idx < (m << 1)) alds4[idx] = src4[idx];
            }
            asm volatile("s_waitcnt lgkmcnt(0)" ::: "memory");

#define EDGE_BODY(JJ, IVJ, HVJ) { \
            HU ua, ub; \
            ua.v = *(const half8v*)&alds[(JJ) * EDGED]; \
            ub.v = *(const half8v*)&alds[(JJ) * EDGED + 8]; \
            float p0 = bgv.x, q0 = 0.f, p1 = bgv.y, q1 = 0.f; \
            p0 = __builtin_amdgcn_fdot2(ua.p[0], w0p[0], p0, false); \
            q0 = __builtin_amdgcn_fdot2(ua.p[1], w0p[1], q0, false); \
            p1 = __builtin_amdgcn_fdot2(ua.p[0], w1p[0], p1, false); \
            q1 = __builtin_amdgcn_fdot2(ua.p[1], w1p[1], q1, false); \
            p0 = __builtin_amdgcn_fdot2(ua.p[2], w0p[2], p0, false); \
            q0 = __builtin_amdgcn_fdot2(ua.p[3], w0p[3], q0, false); \
            p1 = __builtin_amdgcn_fdot2(ua.p[2], w1p[2], p1, false); \
            q1 = __builtin_amdgcn_fdot2(ua.p[3], w1p[3], q1, false); \
            p0 = __builtin_amdgcn_fdot2(ub.p[0], w0p[4], p0, false); \
            q0 = __builtin_amdgcn_fdot2(ub.p[1], w0p[5], q0, false); \
            p1 = __builtin_amdgcn_fdot2(ub.p[0], w1p[4], p1, false); \
            q1 = __builtin_amdgcn_fdot2(ub.p[1], w1p[5], q1, false); \
            p0 = __builtin_amdgcn_fdot2(ub.p[2], w0p[6], p0, false); \
            q0 = __builtin_amdgcn_fdot2(ub.p[3], w0p[7], q0, false); \
            p1 = __builtin_amdgcn_fdot2(ub.p[2], w1p[6], p1, false); \
            q1 = __builtin_amdgcn_fdot2(ub.p[3], w1p[7], q1, false); \
            acc0 += fmaxf(fmaf(p0 + q0, IVJ, btv.x), 0.f) + (float)HVJ.x; \
            acc1 += fmaxf(fmaf(p1 + q1, IVJ, btv.y), 0.f) + (float)HVJ.y; \
        }

            int j = 0;
            for (; j + 4 <= m; j += 4) {
                int v0 = __shfl(sv, j,     64);
                int v1 = __shfl(sv, j + 1, 64);
                int v2 = __shfl(sv, j + 2, 64);
                int v3 = __shfl(sv, j + 3, 64);
                int s_0 = v0 & 0xFFFF, s_1 = v1 & 0xFFFF;
                int s_2 = v2 & 0xFFFF, s_3 = v3 & 0xFFFF;
                float i0 = hi16_to_f(v0);
                float i1 = hi16_to_f(v1);
                float i2 = hi16_to_f(v2);
                float i3 = hi16_to_f(v3);
                half2v h0 = *(const half2v*)&h16[(size_t)s_0 * HD + c0];
                half2v h1 = *(const half2v*)&h16[(size_t)s_1 * HD + c0];
                half2v h2 = *(const half2v*)&h16[(size_t)s_2 * HD + c0];
                half2v h3 = *(const half2v*)&h16[(size_t)s_3 * HD + c0];
                EDGE_BODY(j,     i0, h0);
                EDGE_BODY(j + 1, i1, h1);
                EDGE_BODY(j + 2, i2, h2);
                EDGE_BODY(j + 3, i3, h3);
            }
            for (; j < m; ++j) {
                int vj = __shfl(sv, j, 64);
                int s_ = vj & 0xFFFF;
                float ij = hi16_to_f(vj);
                half2v hj = *(const half2v*)&h16[(size_t)s_ * HD + c0];
                EDGE_BODY(j, ij, hj);
            }
#undef EDGE_BODY
        }
        __bf16 b0 = (__bf16)acc0, b1 = (__bf16)acc1;
        union { __bf16 b[2]; unsigned u; } ph, pl;
        ph.b[0] = b0;
        ph.b[1] = b1;
        pl.b[0] = (__bf16)(acc0 - (float)b0);
        pl.b[1] = (__bf16)(acc1 - (float)b1);
        *(unsigned*)&Ahi[(size_t)n * HD + c0] = ph.u;
        *(unsigned*)&Alo[(size_t)n * HD + c0] = pl.u;
    }
}

// BatchNorm apply from accumulated column sums; input fp16, optional ReLU.
// out16 != null -> write fp16 (h for next layer); else fp32 to out32.
__global__ void bn_k(const _Float16* __restrict__ hl, const float* __restrict__ stats,
                     const float* __restrict__ gam, const float* __restrict__ bet,
                     float* __restrict__ out32, _Float16* __restrict__ out16,
                     int total4, float invN, int relu)
{
    int idx = blockIdx.x * blockDim.x + threadIdx.x;
    if (idx < total4) {
        int c4 = idx & 31;
        half4v xh = *(const half4v*)&hl[(size_t)idx * 4];
        float4 s1 = ((const float4*)stats)[c4];
        float4 s2 = ((const float4*)stats)[32 + c4];
        float4 g  = ((const float4*)gam)[c4];
        float4 b  = ((const float4*)bet)[c4];
        float4 r;
        {
            float m = s1.x * invN; float v = s2.x * invN - m * m;
            r.x = fmaf(((float)xh.x - m) * rsqrtf(v + LN_EPS), g.x, b.x);
        }
        {
            float m = s1.y * invN; float v = s2.y * invN - m * m;
            r.y = fmaf(((float)xh.y - m) * rsqrtf(v + LN_EPS), g.y, b.y);
        }
        {
            float m = s1.z * invN; float v = s2.z * invN - m * m;
            r.z = fmaf(((float)xh.z - m) * rsqrtf(v + LN_EPS), g.z, b.z);
        }
        {
            float m = s1.w * invN; float v = s2.w * invN - m * m;
            r.w = fmaf(((float)xh.w - m) * rsqrtf(v + LN_EPS), g.w, b.w);
        }
        if (relu) {
            r.x = fmaxf(r.x, 0.f); r.y = fmaxf(r.y, 0.f);
            r.z = fmaxf(r.z, 0.f); r.w = fmaxf(r.w, 0.f);
        }
        if (out16) {
            half4v o;
            o.x = (_Float16)r.x; o.y = (_Float16)r.y;
            o.z = (_Float16)r.z; o.w = (_Float16)r.w;
            *(half4v*)&out16[(size_t)idx * 4] = o;
        } else {
            ((float4*)out32)[idx] = r;
        }
    }
}

extern "C" void kernel_launch(void* const* d_in, const int* in_sizes, int n_in,
                              void* d_out, int out_size, void* d_ws, size_t ws_size,
                              hipStream_t stream)
{
    const float* x       = (const float*)d_in[0];
    const int*   ei      = (const int*)d_in[1];
    const float* eattr   = (const float*)d_in[2];
    const float* node_W  = (const float*)d_in[3];
    const float* node_b  = (const float*)d_in[4];
    const float* node_g  = (const float*)d_in[5];
    const float* node_be = (const float*)d_in[6];
    const float* edge_W  = (const float*)d_in[7];
    const float* edge_b  = (const float*)d_in[8];
    const float* edge_g  = (const float*)d_in[9];
    const float* edge_be = (const float*)d_in[10];
    const float* sl_attr = (const float*)d_in[11];
    const float* W1      = (const float*)d_in[12];
    const float* b1      = (const float*)d_in[13];
    const float* W2      = (const float*)d_in[14];
    const float* b2      = (const float*)d_in[15];
    const float* bn_g    = (const float*)d_in[16];
    const float* bn_b    = (const float*)d_in[17];

    const int N = in_sizes[0] / NODED;
    const int E = in_sizes[1] / 2;

    // explicit 16B-aligned workspace layout
    char* base = (char*)d_ws;
    size_t off = 0;
    auto take = [&](size_t nbytes) -> void* {
        void* p = base + off;
        off = (off + nbytes + 15) & ~(size_t)15;
        return p;
    };
    _Float16* h16  = (_Float16*)take((size_t)N * HD * 2); // node features (fp16)
    _Float16* hl16 = (_Float16*)take((size_t)N * HD * 2); // mlp2 out (pre-BN, fp16)
    __bf16* aghi   = (__bf16*)take((size_t)N * HD * 2);    // aggr bf16 hi
    __bf16* aglo   = (__bf16*)take((size_t)N * HD * 2);
    __bf16* xhi    = (__bf16*)take((size_t)N * NODED * 2);
    __bf16* xlo    = (__bf16*)take((size_t)N * NODED * 2);
    float*  slv3   = (float*)take(3 * HD * 4);
    float*  stats  = (float*)take(3 * 256 * 4);
    int*    cnt    = (int*)take((size_t)N * 4);
    int*    cursor = (int*)take((size_t)N * 4);
    int*    bsum   = (int*)take(256 * 4);
    int*    boff   = (int*)take(256 * 4);
    int*    rs     = (int*)take(((size_t)N + 2) * 4);
    int2*   es     = (int2*)take((size_t)E * 8);
    unsigned* sei  = (unsigned*)take((size_t)3 * E * 4);   // packed (src16, iv-fp16)
    _Float16* attr16 = (_Float16*)take((size_t)E * EDGED * 2); // slot-permuted fp16 attrs
    _Float16* Wg16_3 = (_Float16*)take(3 * 2048 * 2);      // fp16 edge weights [c][k]
    float*  bg3    = (float*)take(3 * HD * 4);
    float*  M3     = (float*)take(3 * 256 * 4);
    float*  v3     = (float*)take(3 * 16 * 4);
    float*  s03    = (float*)take(4 * 4);
    __bf16* nWhi   = (__bf16*)take((size_t)HD * NODED * 2);
    __bf16* nWlo   = (__bf16*)take((size_t)HD * NODED * 2);
    __bf16* W1hi   = (__bf16*)take((size_t)3 * 256 * HD * 2);
    __bf16* W1lo   = (__bf16*)take((size_t)3 * 256 * HD * 2);
    _Float16* W2h16 = (_Float16*)take((size_t)3 * HD * 256 * 2);
    _Float16* W2l16 = (_Float16*)take((size_t)3 * HD * 256 * 2);

    // weight splits: node/W1 bf16 hi/lo, W2 fp16 hi/lo, x bf16 hi/lo
    wconv_k<<<(HD * NODED + 255) / 256, 256, 0, stream>>>(node_W, nWhi, nWlo, HD * NODED);
    wconv_k<<<(3 * 256 * HD + 255) / 256, 256, 0, stream>>>(W1, W1hi, W1lo, 3 * 256 * HD);
    wconv16_k<<<(3 * 256 * HD + 255) / 256, 256, 0, stream>>>(W2, W2h16, W2l16, 3 * 256 * HD);
    wconv_k<<<((int)((size_t)N * NODED + 255) / 256), 256, 0, stream>>>(x, xhi, xlo, N * NODED);

    // edge-LN precompute + self-loop embed + fp16 weights (all 3 layers)
    prep_k<<<3, 256, 0, stream>>>(edge_W, edge_b, edge_g, edge_be, sl_attr,
                                  Wg16_3, bg3, M3, v3, s03, slv3);

    // ---- CSR build ----
    const int eblocks = (E + 255) / 256;
    const int nblocks = (N + 255) / 256;
    hipMemsetAsync(cnt, 0, (size_t)N * sizeof(int), stream);
    hist_k<<<eblocks, 256, 0, stream>>>(ei, cnt, E);
    scan1_k<<<nblocks, 256, 0, stream>>>(cnt, rs, bsum, N);
    scan2_k<<<1, 256, 0, stream>>>(bsum, boff, nblocks);
    scan3_k<<<nblocks, 256, 0, stream>>>(rs, cursor, boff, N, E);
    scatter_k<<<eblocks, 256, 0, stream>>>(ei, cursor, es, E);

    // per-slot packed (src, iv) for all 3 layers + permuted fp16 attr stream
    einv_k<<<eblocks, 256, 0, stream>>>(es, eattr, M3, v3, s03, sei, attr16, E);

    const int total4  = N * (HD / 4);
    const int vblocks = (total4 + 255) / 256;
    const int gb128   = (N + 127) / 128;
    int pgrid = (N + 3) / 4;
    if (pgrid > 2048) pgrid = 2048;           // persistent: 8192 waves

    // node embed: fused Linear (MFMA) + LN + ReLU -> fp16 h
    nemb_k<<<gb128, 256, 0, stream>>>(xhi, xlo, nWhi, nWlo, node_b,
                                      node_g, node_be, h16, N);

    hipMemsetAsync(stats, 0, 3 * 256 * sizeof(float), stream);

    for (int l = 0; l < 3; ++l) {
        pull9_k<<<pgrid, 256, 0, stream>>>(h16, rs, attr16, sei + (size_t)l * E,
                                           slv3 + l * HD, Wg16_3 + (size_t)l * 2048,
                                           bg3 + l * HD, edge_be + l * HD,
                                           aghi, aglo, N);

        // fused mlp1+mlp2: aggr -> gelu(z) in LDS -> hl16 + stats
        fmlp_k<<<gb128, 256, 0, stream>>>(
            aghi, aglo, W1hi + (size_t)l * 256 * HD, W1lo + (size_t)l * 256 * HD,
            b1 + l * 256, W2h16 + (size_t)l * HD * 256, W2l16 + (size_t)l * HD * 256,
            b2 + l * HD, hl16, N, stats + l * 256);

        bn_k<<<vblocks, 256, 0, stream>>>(hl16, stats + l * 256,
                                          bn_g + l * HD, bn_b + l * HD,
                                          (float*)d_out, (l < 2) ? h16 : nullptr,
                                          total4, 1.f / N, (l < 2) ? 1 : 0);
    }
}